// Round 5
// baseline (186.430 us; speedup 1.0000x reference)
//
#include <hip/hip_runtime.h>
#include <hip/hip_bf16.h>
#include <stdint.h>

#define B_SZ 1024
#define N_SZ 65536
#define M_SZ 128

typedef short bf16x8 __attribute__((ext_vector_type(8)));
typedef short bf16x4 __attribute__((ext_vector_type(4)));
typedef float f32x4 __attribute__((ext_vector_type(4)));

__device__ __forceinline__ unsigned short f2bf(float f) {
    uint32_t u = __float_as_uint(f);
    uint32_t r = (u + 0x7FFFu + ((u >> 16) & 1u)) >> 16;  // RNE
    return (unsigned short)r;
}

// ---- kernel 0 (fused): blocks 0..255 transpose E||D -> EDt[c][b] bf16; 256..383 zero out.
__global__ __launch_bounds__(256) void k_edt(const float* __restrict__ E,
                                             const float* __restrict__ D,
                                             unsigned short* __restrict__ EDt,
                                             float* __restrict__ out) {
    if (blockIdx.x >= 256) {
        int i = (blockIdx.x - 256) * 1024 + threadIdx.x * 4;
        *(float4*)(out + i) = (float4){0.f, 0.f, 0.f, 0.f};
        return;
    }
    __shared__ float tile[32][33];
    int bx = blockIdx.x & 31;
    int cy = blockIdx.x >> 5;
    int b0 = bx * 32, c0 = cy * 32;
    const float* src = (c0 < M_SZ) ? E : D;
    int cs0 = c0 & (M_SZ - 1);
    int t = threadIdx.x;
    int i = t >> 3, j = (t & 7) * 4;
    const float* p = src + (size_t)(b0 + i) * M_SZ + cs0 + j;
    float4 v = *(const float4*)p;
    tile[i][j] = v.x; tile[i][j + 1] = v.y; tile[i][j + 2] = v.z; tile[i][j + 3] = v.w;
    __syncthreads();
    int c = t >> 3, b4 = (t & 7) * 4;
    unsigned short* q = EDt + (size_t)(c0 + c) * B_SZ + b0 + b4;
    ushort4 o;
    o.x = f2bf(tile[b4 + 0][c]); o.y = f2bf(tile[b4 + 1][c]);
    o.z = f2bf(tile[b4 + 2][c]); o.w = f2bf(tile[b4 + 3][c]);
    *(ushort4*)q = o;
}

// =======================  PASS 1  =======================
// NCt[m][n] = C[n][m]*(1-W) + V,  (W|V) = A^T @ (E||D)
// block: 128 n x 256 c, K=1024 in 32-chunks, double-buffered reg-staged.
// As32: [128 n][20 u32] — u32 p holds bf16 k-pair (2p,2p+1); 16-B groups
// XOR-swizzled by s(n)=((n>>2)^(n>>4))&3. Frag read = 1 ds_read_b128 per fi.
// EDs: [256 c][40] bf16, k-contiguous rows.
#define AS_U32 (128 * 20)
#define ED_LD 40

__device__ __forceinline__ int a_swz(int n, int p) {  // p = dword idx 0..15
    int s = ((n >> 2) ^ (n >> 4)) & 3;
    return n * 20 + (p ^ (s << 2));
}

__global__ __launch_bounds__(256, 2) void k_pass1(
    const float* __restrict__ A,            // [B][N]
    const unsigned short* __restrict__ EDt, // [256][B] bf16
    const float* __restrict__ C,            // [N][M]
    unsigned short* __restrict__ NCt)       // [M][N] bf16 out (transposed)
{
    __shared__ __align__(16) uint32_t As32[2][AS_U32];
    __shared__ __align__(16) unsigned short EDs[2][256 * ED_LD];
    const int t = threadIdx.x;
    const int lane = t & 63;
    const int wv = t >> 6;
    const int wvn = wv >> 1, wvc = wv & 1;
    const int g = lane >> 4;
    const int m16 = lane & 15;
    const int n0 = blockIdx.x * 128;

    // staging roles
    const int pp = t >> 4;          // k-pair 0..15 (rows 2pp, 2pp+1)
    const int sub = t & 15;         // n-span sub*8..+8
    const int colq = t >> 3;        // ED col 0..31 (+32*p8)
    const int seg = t & 7;          // ED 4-short segment

    int cb[8];
#pragma unroll
    for (int fj = 0; fj < 4; ++fj) { cb[fj] = wvc * 4 + fj; cb[fj + 4] = 8 + wvc * 4 + fj; }

    f32x4 acc[4][8];
#pragma unroll
    for (int i = 0; i < 4; ++i)
#pragma unroll
        for (int j = 0; j < 8; ++j) acc[i][j] = (f32x4){0.f, 0.f, 0.f, 0.f};

    // ---- prologue: stage chunk 0 into buf 0
    {
        const float* r0 = A + (size_t)(2 * pp) * N_SZ + n0 + sub * 8;
        const float* r1 = r0 + N_SZ;
        float4 a0 = ((const float4*)r0)[0], a1 = ((const float4*)r0)[1];
        float4 b0v = ((const float4*)r1)[0], b1v = ((const float4*)r1)[1];
        float r0v[8] = {a0.x,a0.y,a0.z,a0.w,a1.x,a1.y,a1.z,a1.w};
        float r1v[8] = {b0v.x,b0v.y,b0v.z,b0v.w,b1v.x,b1v.y,b1v.z,b1v.w};
#pragma unroll
        for (int j = 0; j < 8; ++j) {
            int n = sub * 8 + j;
            uint32_t v = (uint32_t)f2bf(r0v[j]) | ((uint32_t)f2bf(r1v[j]) << 16);
            As32[0][a_swz(n, pp)] = v;
        }
#pragma unroll
        for (int p8 = 0; p8 < 8; ++p8) {
            int col = p8 * 32 + colq;
            ushort4 v = *(const ushort4*)(EDt + (size_t)col * B_SZ + seg * 4);
            *(ushort4*)&EDs[0][col * ED_LD + seg * 4] = v;
        }
    }
    __syncthreads();

    int cur = 0;
    for (int bk = 0; bk < B_SZ; bk += 32) {
        const bool last = (bk + 32 >= B_SZ);
        const int nk = last ? 0 : bk + 32;

        // (1) prefetch next chunk -> regs
        const float* r0 = A + (size_t)(nk + 2 * pp) * N_SZ + n0 + sub * 8;
        const float* r1 = r0 + N_SZ;
        float4 a0 = ((const float4*)r0)[0], a1 = ((const float4*)r0)[1];
        float4 b0v = ((const float4*)r1)[0], b1v = ((const float4*)r1)[1];
        ushort4 e[8];
#pragma unroll
        for (int p8 = 0; p8 < 8; ++p8) {
            int col = p8 * 32 + colq;
            e[p8] = *(const ushort4*)(EDt + (size_t)col * B_SZ + nk + seg * 4);
        }

        // (2) fragment reads from buf[cur]
        bf16x8 af[4];
#pragma unroll
        for (int fi = 0; fi < 4; ++fi) {
            int n = wvn * 64 + fi * 16 + m16;
            int s = ((n >> 2) ^ (n >> 4)) & 3;
            af[fi] = *(const bf16x8*)&As32[cur][n * 20 + ((g ^ s) << 2)];
        }
        bf16x8 bfr[8];
#pragma unroll
        for (int fj = 0; fj < 8; ++fj)
            bfr[fj] = *(const bf16x8*)&EDs[cur][(cb[fj] * 16 + m16) * ED_LD + g * 8];

        // (3) MFMAs
#pragma unroll
        for (int fj = 0; fj < 8; ++fj)
#pragma unroll
            for (int fi = 0; fi < 4; ++fi)
                acc[fi][fj] = __builtin_amdgcn_mfma_f32_16x16x32_bf16(af[fi], bfr[fj], acc[fi][fj], 0, 0, 0);

        // (4) convert + write next buffer
        if (!last) {
            const int nxt = cur ^ 1;
            float r0v[8] = {a0.x,a0.y,a0.z,a0.w,a1.x,a1.y,a1.z,a1.w};
            float r1v[8] = {b0v.x,b0v.y,b0v.z,b0v.w,b1v.x,b1v.y,b1v.z,b1v.w};
#pragma unroll
            for (int j = 0; j < 8; ++j) {
                int n = sub * 8 + j;
                uint32_t v = (uint32_t)f2bf(r0v[j]) | ((uint32_t)f2bf(r1v[j]) << 16);
                As32[nxt][a_swz(n, pp)] = v;
            }
#pragma unroll
            for (int p8 = 0; p8 < 8; ++p8) {
                int col = p8 * 32 + colq;
                *(ushort4*)&EDs[nxt][col * ED_LD + seg * 4] = e[p8];
            }
        }
        __syncthreads();
        cur ^= 1;
    }

    // epilogue: D layout col=lane&15, row=(lane>>4)*4+r. NCt[m][n]: n contiguous per lane.
#pragma unroll
    for (int fi = 0; fi < 4; ++fi)
#pragma unroll
        for (int fj = 0; fj < 4; ++fj) {
            int n_base = n0 + wvn * 64 + fi * 16 + g * 4;
            int m = wvc * 64 + fj * 16 + m16;
            bf16x4 o;
#pragma unroll
            for (int r = 0; r < 4; ++r) {
                float w = acc[fi][fj][r];
                float v = acc[fi][fj + 4][r];
                float cc = C[(size_t)(n_base + r) * M_SZ + m];
                o[r] = (short)f2bf(cc * (1.0f - w) + v);
            }
            *(bf16x4*)&NCt[(size_t)m * N_SZ + n_base] = o;
        }
}

// =======================  PASS 2  =======================
// out[b][m] += A[b][k] * NCt[m][k]; block = 128b x 128m, 64 K-splits x 1024.
// Depth-2 prefetch, fully linear LDS, XCD-grouped k-splits.
// Staging coverage: 256 thr x 16 k-elem = 128 rows x 32 k (2 thr/row). DO NOT SHRINK.
#define L2_LD 40
#define NCHUNK 32

__global__ __launch_bounds__(256, 2) void k_pass2(
    const float* __restrict__ A,
    const unsigned short* __restrict__ NCt,  // [M][N]
    float* __restrict__ out)
{
    __shared__ __align__(16) unsigned short As2[2][128 * L2_LD];
    __shared__ __align__(16) unsigned short NCs[2][128 * L2_LD];
    const int t = threadIdx.x;
    const int lane = t & 63;
    const int wv = t >> 6;
    const int wvb = wv >> 1, wvm = wv & 1;
    const int g = lane >> 4;
    const int m16 = lane & 15;
    // XCD grouping: same-k0 blocks (bid = kgrp mod 64) share XCD (bid%8 = kgrp%8).
    const int k0 = (blockIdx.x & 63) << 10;
    const int b0 = (7 - (blockIdx.x >> 6)) << 7;   // reversed: catch L3 tail of A

    const int row = t >> 1, half = t & 1;

    f32x4 acc[4][4];
#pragma unroll
    for (int i = 0; i < 4; ++i)
#pragma unroll
        for (int j = 0; j < 4; ++j) acc[i][j] = (f32x4){0.f, 0.f, 0.f, 0.f};

    float4 ra[2][4];   // [slot][q] A fp32 — 16 floats = full 16-k half-row
    uint4  rn[2][2];   // [slot][q] NCt bf16 — 16 bf16

    // prologue: load chunks 0,1; write chunk 0 -> buf0
#pragma unroll
    for (int c = 0; c < 2; ++c) {
        const float* p = A + (size_t)(b0 + row) * N_SZ + k0 + c * 32 + half * 16;
        ra[c][0] = ((const float4*)p)[0]; ra[c][1] = ((const float4*)p)[1];
        ra[c][2] = ((const float4*)p)[2]; ra[c][3] = ((const float4*)p)[3];
        const uint4* pn = (const uint4*)(NCt + (size_t)row * N_SZ + k0 + c * 32 + half * 16);
        rn[c][0] = pn[0]; rn[c][1] = pn[1];
    }
    {
        ushort4* w = (ushort4*)&As2[0][row * L2_LD + half * 16];
        ushort4 o;
        o.x = f2bf(ra[0][0].x); o.y = f2bf(ra[0][0].y); o.z = f2bf(ra[0][0].z); o.w = f2bf(ra[0][0].w); w[0] = o;
        o.x = f2bf(ra[0][1].x); o.y = f2bf(ra[0][1].y); o.z = f2bf(ra[0][1].z); o.w = f2bf(ra[0][1].w); w[1] = o;
        o.x = f2bf(ra[0][2].x); o.y = f2bf(ra[0][2].y); o.z = f2bf(ra[0][2].z); o.w = f2bf(ra[0][2].w); w[2] = o;
        o.x = f2bf(ra[0][3].x); o.y = f2bf(ra[0][3].y); o.z = f2bf(ra[0][3].z); o.w = f2bf(ra[0][3].w); w[3] = o;
        uint4* wn = (uint4*)&NCs[0][row * L2_LD + half * 16];
        wn[0] = rn[0][0]; wn[1] = rn[0][1];
    }
    __syncthreads();

#pragma unroll 2
    for (int c = 0; c < NCHUNK; ++c) {
        // (1) issue loads for chunk c+2 into slot c&1 (chunk c already in LDS)
        if (c + 2 < NCHUNK) {
            const float* p = A + (size_t)(b0 + row) * N_SZ + k0 + (c + 2) * 32 + half * 16;
            ra[c & 1][0] = ((const float4*)p)[0]; ra[c & 1][1] = ((const float4*)p)[1];
            ra[c & 1][2] = ((const float4*)p)[2]; ra[c & 1][3] = ((const float4*)p)[3];
            const uint4* pn = (const uint4*)(NCt + (size_t)row * N_SZ + k0 + (c + 2) * 32 + half * 16);
            rn[c & 1][0] = pn[0]; rn[c & 1][1] = pn[1];
        }

        // (2) fragment reads + MFMA on buf[c&1]
        bf16x8 af[4];
#pragma unroll
        for (int fi = 0; fi < 4; ++fi)
            af[fi] = *(const bf16x8*)&As2[c & 1][(wvb * 64 + fi * 16 + m16) * L2_LD + g * 8];
        bf16x8 bfr[4];
#pragma unroll
        for (int fj = 0; fj < 4; ++fj)
            bfr[fj] = *(const bf16x8*)&NCs[c & 1][(wvm * 64 + fj * 16 + m16) * L2_LD + g * 8];
#pragma unroll
        for (int fi = 0; fi < 4; ++fi)
#pragma unroll
            for (int fj = 0; fj < 4; ++fj)
                acc[fi][fj] = __builtin_amdgcn_mfma_f32_16x16x32_bf16(af[fi], bfr[fj], acc[fi][fj], 0, 0, 0);

        // (3) write chunk c+1 (slot (c+1)&1) -> buf[(c+1)&1]
        if (c + 1 < NCHUNK) {
            const int s = (c + 1) & 1;
            ushort4* w = (ushort4*)&As2[s][row * L2_LD + half * 16];
            ushort4 o;
            o.x = f2bf(ra[s][0].x); o.y = f2bf(ra[s][0].y); o.z = f2bf(ra[s][0].z); o.w = f2bf(ra[s][0].w); w[0] = o;
            o.x = f2bf(ra[s][1].x); o.y = f2bf(ra[s][1].y); o.z = f2bf(ra[s][1].z); o.w = f2bf(ra[s][1].w); w[1] = o;
            o.x = f2bf(ra[s][2].x); o.y = f2bf(ra[s][2].y); o.z = f2bf(ra[s][2].z); o.w = f2bf(ra[s][2].w); w[2] = o;
            o.x = f2bf(ra[s][3].x); o.y = f2bf(ra[s][3].y); o.z = f2bf(ra[s][3].z); o.w = f2bf(ra[s][3].w); w[3] = o;
            uint4* wn = (uint4*)&NCs[s][row * L2_LD + half * 16];
            wn[0] = rn[s][0]; wn[1] = rn[s][1];
        }
        __syncthreads();
    }

#pragma unroll
    for (int fi = 0; fi < 4; ++fi)
#pragma unroll
        for (int fj = 0; fj < 4; ++fj)
#pragma unroll
            for (int r = 0; r < 4; ++r) {
                int b = b0 + wvb * 64 + fi * 16 + g * 4 + r;
                int m = wvm * 64 + fj * 16 + m16;
                atomicAdd(out + (size_t)b * M_SZ + m, acc[fi][fj][r]);
            }
}

extern "C" void kernel_launch(void* const* d_in, const int* in_sizes, int n_in,
                              void* d_out, int out_size, void* d_ws, size_t ws_size,
                              hipStream_t stream) {
    const float* A  = (const float*)d_in[0];   // address [B,N]
    const float* E  = (const float*)d_in[1];   // erase   [B,M]
    const float* Dd = (const float*)d_in[2];   // add     [B,M]
    const float* C  = (const float*)d_in[3];   // content [N,M]
    float* out = (float*)d_out;

    unsigned short* NCt = (unsigned short*)d_ws;                                     // 16 MB [M][N]
    unsigned short* EDt = (unsigned short*)((char*)d_ws + (size_t)M_SZ * N_SZ * 2);  // +512 KB

    k_edt <<<384, 256, 0, stream>>>(E, Dd, EDt, out);
    k_pass1<<<512, 256, 0, stream>>>(A, EDt, C, NCt);
    k_pass2<<<512, 256, 0, stream>>>(A, NCt, out);
}